// Round 1
// baseline (469.658 us; speedup 1.0000x reference)
//
#include <hip/hip_runtime.h>
#include <hip/hip_bf16.h>

typedef float  f32x4  __attribute__((ext_vector_type(4)));
typedef __bf16 bf16x8 __attribute__((ext_vector_type(8)));
typedef __bf16 bf16x4 __attribute__((ext_vector_type(4)));

#define D_  512
#define H_  8
#define HD_ 64
#define B_  256
#define N_  144
#define M_  (B_*N_)   // 36864

// ---------------- weight prep: f32 -> bf16 ----------------
__global__ void prep_weights_kernel(const float* __restrict__ kvw,
                                    const float* __restrict__ qw,
                                    const float* __restrict__ pw,
                                    __bf16* __restrict__ kvb,
                                    __bf16* __restrict__ qb,
                                    __bf16* __restrict__ pb) {
    int idx = blockIdx.x * 256 + threadIdx.x;   // 262144 threads, 4 elements each
    const float* s; __bf16* d; int off;
    if (idx < 131072)      { s = kvw; d = kvb; off = idx; }
    else if (idx < 196608) { s = qw;  d = qb;  off = idx - 131072; }
    else                   { s = pw;  d = pb;  off = idx - 196608; }
    f32x4 v = *(const f32x4*)(s + (size_t)off * 4);
    bf16x4 o;
    o[0] = (__bf16)v.x; o[1] = (__bf16)v.y; o[2] = (__bf16)v.z; o[3] = (__bf16)v.w;
    *(bf16x4*)(d + (size_t)off * 4) = o;
}

// ---------------- GEMM: C[M,Nout] = A[M,512] @ Bw[Nout,512]^T ----------------
// MODE 1: A = x + is_end*topo (f32->bf16), out -> k_buf [B,H,N,64] & vT_buf [B,H,64,N]
// MODE 2: A = x (f32->bf16),              out -> q_buf [B,H,N,64]
// MODE 3: A = attn_out (bf16),            out -> f32 [M,512] + bias
template<int MODE>
__launch_bounds__(256, 2)
__global__ void gemm_kernel(const float* __restrict__ Af0,
                            const float* __restrict__ Af1,
                            const __bf16* __restrict__ Abf,
                            const __bf16* __restrict__ Bw,
                            __bf16* __restrict__ kout,
                            __bf16* __restrict__ vTout,
                            __bf16* __restrict__ qout,
                            float*  __restrict__ pout,
                            const float* __restrict__ bias,
                            const int* __restrict__ is_end) {
    __shared__ __bf16 As[128][72];   // +8 pad: frag reads <=2-way bank conflict
    __shared__ __bf16 Bs[128][72];

    const int tid  = threadIdx.x;
    const int lane = tid & 63;
    const int wid  = tid >> 6;
    const int lrow = lane & 15, lhi = lane >> 4;
    const int wr   = wid >> 1,  wc  = wid & 1;
    const int m0   = blockIdx.x * 128;
    const int n0   = blockIdx.y * 128;

    float tf = 0.f;
    if (MODE == 1) tf = (is_end[0] != 0) ? 1.f : 0.f;

    f32x4 acc[4][4];
#pragma unroll
    for (int i = 0; i < 4; ++i)
#pragma unroll
        for (int j = 0; j < 4; ++j) acc[i][j] = (f32x4){0.f, 0.f, 0.f, 0.f};

    for (int kt = 0; kt < 8; ++kt) {
        const int k0 = kt * 64;
        // ---- stage A and B tiles (reg-staged, cast to bf16) ----
#pragma unroll
        for (int it = 0; it < 4; ++it) {
            int c = tid + it * 256;       // 0..1023 chunks of 8 elements
            int row = c >> 3, cc = c & 7;
            if (MODE == 3) {
                bf16x8 v = *(const bf16x8*)(Abf + (size_t)(m0 + row) * D_ + k0 + cc * 8);
                *(bf16x8*)&As[row][cc * 8] = v;
            } else {
                const float* ap = Af0 + (size_t)(m0 + row) * D_ + k0 + cc * 8;
                f32x4 v0 = *(const f32x4*)ap;
                f32x4 v1 = *(const f32x4*)(ap + 4);
                if (MODE == 1) {
                    const float* tp = Af1 + (size_t)(m0 + row) * D_ + k0 + cc * 8;
                    f32x4 t0 = *(const f32x4*)tp;
                    f32x4 t1 = *(const f32x4*)(tp + 4);
                    v0 = v0 + t0 * tf;
                    v1 = v1 + t1 * tf;
                }
                bf16x8 o;
                o[0] = (__bf16)v0.x; o[1] = (__bf16)v0.y; o[2] = (__bf16)v0.z; o[3] = (__bf16)v0.w;
                o[4] = (__bf16)v1.x; o[5] = (__bf16)v1.y; o[6] = (__bf16)v1.z; o[7] = (__bf16)v1.w;
                *(bf16x8*)&As[row][cc * 8] = o;
            }
            bf16x8 bv = *(const bf16x8*)(Bw + (size_t)(n0 + row) * D_ + k0 + cc * 8);
            *(bf16x8*)&Bs[row][cc * 8] = bv;
        }
        __syncthreads();
        // ---- MFMA inner loop ----
#pragma unroll
        for (int kk = 0; kk < 2; ++kk) {
            bf16x8 af[4], bfr[4];
#pragma unroll
            for (int mi = 0; mi < 4; ++mi)
                af[mi] = *(const bf16x8*)&As[wr * 64 + mi * 16 + lrow][kk * 32 + lhi * 8];
#pragma unroll
            for (int ni = 0; ni < 4; ++ni)
                bfr[ni] = *(const bf16x8*)&Bs[wc * 64 + ni * 16 + lrow][kk * 32 + lhi * 8];
#pragma unroll
            for (int mi = 0; mi < 4; ++mi)
#pragma unroll
                for (int ni = 0; ni < 4; ++ni)
                    acc[mi][ni] = __builtin_amdgcn_mfma_f32_16x16x32_bf16(
                        af[mi], bfr[ni], acc[mi][ni], 0, 0, 0);
        }
        __syncthreads();
    }

    // ---- epilogue: C row = (lane>>4)*4+reg, col = lane&15 (m89-verified layout) ----
    float bv4[4];
    if (MODE == 3) {
#pragma unroll
        for (int ni = 0; ni < 4; ++ni) bv4[ni] = bias[n0 + wc * 64 + ni * 16 + lrow];
    }
#pragma unroll
    for (int mi = 0; mi < 4; ++mi) {
#pragma unroll
        for (int reg = 0; reg < 4; ++reg) {
            int m  = m0 + wr * 64 + mi * 16 + lhi * 4 + reg;
            int bb = m / N_;
            int nn = m - bb * N_;
#pragma unroll
            for (int ni = 0; ni < 4; ++ni) {
                int o = n0 + wc * 64 + ni * 16 + lrow;
                float val = acc[mi][ni][reg];
                if (MODE == 1) {
                    int hh = (o >> 6) & 7;
                    int dd = o & 63;
                    if (o < 512)
                        kout[(((size_t)bb * H_ + hh) * N_ + nn) * HD_ + dd] = (__bf16)val;
                    else
                        vTout[(((size_t)bb * H_ + hh) * HD_ + dd) * N_ + nn] = (__bf16)val;
                } else if (MODE == 2) {
                    int hh = o >> 6, dd = o & 63;
                    qout[(((size_t)bb * H_ + hh) * N_ + nn) * HD_ + dd] = (__bf16)val;
                } else {
                    pout[(size_t)m * D_ + o] = val + bv4[ni];
                }
            }
        }
    }
}

// ---------------- attention: one block per (b,h) ----------------
__launch_bounds__(256, 2)
__global__ void attn_kernel(const __bf16* __restrict__ qbuf,
                            const __bf16* __restrict__ kbuf,
                            const __bf16* __restrict__ vTbuf,
                            __bf16* __restrict__ aout) {
    __shared__ __bf16 Ks[144][72];     // 20736 B
    __shared__ __bf16 Vs[64][168];     // 21504 B (cols 144..167 zero)
    __shared__ __bf16 Ps[4][16][160];  // 20480 B per-wave P tiles

    const int tid  = threadIdx.x;
    const int lane = tid & 63, wid = tid >> 6;
    const int lrow = lane & 15, lhi = lane >> 4;
    const int bh = blockIdx.x;
    const int bb = bh >> 3, hh = bh & 7;

    const __bf16* kg = kbuf  + (size_t)bh * (N_ * HD_);
    const __bf16* vg = vTbuf + (size_t)bh * (N_ * HD_);
    const __bf16* qg = qbuf  + (size_t)bh * (N_ * HD_);

    for (int c = tid; c < 1152; c += 256) {       // K: 144x64
        int row = c >> 3, cc = c & 7;
        *(bf16x8*)&Ks[row][cc * 8] = *(const bf16x8*)(kg + row * 64 + cc * 8);
    }
    for (int c = tid; c < 1152; c += 256) {       // vT: 64x144
        int dd = c / 18, cc = c - dd * 18;
        *(bf16x8*)&Vs[dd][cc * 8] = *(const bf16x8*)(vg + dd * 144 + cc * 8);
    }
    bf16x8 z8;
#pragma unroll
    for (int i = 0; i < 8; ++i) z8[i] = (__bf16)0.f;
    if (tid < 192) {                              // zero pad cols of Vs
        int dd = tid / 3, cc = tid - dd * 3;
        *(bf16x8*)&Vs[dd][144 + cc * 8] = z8;
    }
    if (lhi < 2)                                  // zero pad cols of this wave's Ps
        *(bf16x8*)&Ps[wid][lrow][144 + lhi * 8] = z8;
    __syncthreads();

    const float sc = 0.125f * 1.44269504089f;     // scale * log2(e)

    for (int t = wid; t < 9; t += 4) {            // 16-row tiles of Q
        bf16x8 aq[2];
#pragma unroll
        for (int kk = 0; kk < 2; ++kk)
            aq[kk] = *(const bf16x8*)(qg + (t * 16 + lrow) * 64 + kk * 32 + lhi * 8);

        f32x4 s[9];
#pragma unroll
        for (int j = 0; j < 9; ++j) s[j] = (f32x4){0.f, 0.f, 0.f, 0.f};
#pragma unroll
        for (int j = 0; j < 9; ++j)
#pragma unroll
            for (int kk = 0; kk < 2; ++kk)
                s[j] = __builtin_amdgcn_mfma_f32_16x16x32_bf16(
                    aq[kk], *(const bf16x8*)&Ks[j * 16 + lrow][kk * 32 + lhi * 8], s[j], 0, 0, 0);

        // wave-parallel softmax: rows = lhi*4+reg, cols spread over 16 lanes x 9 frags
        float inv[4];
#pragma unroll
        for (int reg = 0; reg < 4; ++reg) {
            float mx = s[0][reg];
#pragma unroll
            for (int j = 1; j < 9; ++j) mx = fmaxf(mx, s[j][reg]);
#pragma unroll
            for (int off = 1; off < 16; off <<= 1) mx = fmaxf(mx, __shfl_xor(mx, off, 16));
            float sum = 0.f;
#pragma unroll
            for (int j = 0; j < 9; ++j) {
                float p = exp2f((s[j][reg] - mx) * sc);
                s[j][reg] = p;
                sum += p;
            }
#pragma unroll
            for (int off = 1; off < 16; off <<= 1) sum += __shfl_xor(sum, off, 16);
            inv[reg] = 1.f / sum;
        }
        // write normalized P (bf16) to this wave's LDS tile
#pragma unroll
        for (int j = 0; j < 9; ++j)
#pragma unroll
            for (int reg = 0; reg < 4; ++reg)
                Ps[wid][lhi * 4 + reg][j * 16 + lrow] = (__bf16)(s[j][reg] * inv[reg]);

        // PV: out[16,64] = P[16,160] @ V[160,64]  (K padded with zeros)
#pragma unroll
        for (int dc = 0; dc < 4; ++dc) {
            f32x4 o4 = (f32x4){0.f, 0.f, 0.f, 0.f};
#pragma unroll
            for (int kc = 0; kc < 5; ++kc)
                o4 = __builtin_amdgcn_mfma_f32_16x16x32_bf16(
                    *(const bf16x8*)&Ps[wid][lrow][kc * 32 + lhi * 8],
                    *(const bf16x8*)&Vs[dc * 16 + lrow][kc * 32 + lhi * 8], o4, 0, 0, 0);
#pragma unroll
            for (int reg = 0; reg < 4; ++reg) {
                int nn = t * 16 + lhi * 4 + reg;
                int dd = dc * 16 + lrow;
                aout[((size_t)bb * N_ + nn) * D_ + hh * HD_ + dd] = (__bf16)o4[reg];
            }
        }
    }
}

extern "C" void kernel_launch(void* const* d_in, const int* in_sizes, int n_in,
                              void* d_out, int out_size, void* d_ws, size_t ws_size,
                              hipStream_t stream) {
    const float* x      = (const float*)d_in[0];
    const float* topo   = (const float*)d_in[1];
    const float* kvw    = (const float*)d_in[2];
    const float* qw     = (const float*)d_in[3];
    const float* pw     = (const float*)d_in[4];
    const float* pb     = (const float*)d_in[5];
    const int*   is_end = (const int*)d_in[6];
    float* out = (float*)d_out;

    char* ws = (char*)d_ws;
    __bf16* kvb = (__bf16*)(ws);                       // 1 MiB
    __bf16* qb  = (__bf16*)(ws + (1u << 20));          // 512 KiB
    __bf16* pwb = (__bf16*)(ws + (1u << 20) + 524288); // 512 KiB
    size_t off = (1u << 20) + 2 * 524288;
    const size_t BUF = (size_t)M_ * D_ * 2;            // 37748736 B each
    __bf16* kbuf  = (__bf16*)(ws + off); off += BUF;
    __bf16* vTbuf = (__bf16*)(ws + off); off += BUF;
    __bf16* qbuf  = (__bf16*)(ws + off); off += BUF;
    __bf16* abuf  = (__bf16*)(ws + off); off += BUF;

    prep_weights_kernel<<<1024, 256, 0, stream>>>(kvw, qw, pw, kvb, qb, pwb);
    gemm_kernel<1><<<dim3(288, 8), 256, 0, stream>>>(x, topo, nullptr, kvb,
                                                     kbuf, vTbuf, nullptr, nullptr,
                                                     nullptr, is_end);
    gemm_kernel<2><<<dim3(288, 4), 256, 0, stream>>>(x, nullptr, nullptr, qb,
                                                     nullptr, nullptr, qbuf, nullptr,
                                                     nullptr, nullptr);
    attn_kernel<<<2048, 256, 0, stream>>>(qbuf, kbuf, vTbuf, abuf);
    gemm_kernel<3><<<dim3(288, 4), 256, 0, stream>>>(nullptr, nullptr, abuf, pwb,
                                                     nullptr, nullptr, nullptr, out,
                                                     pb, nullptr);
}

// Round 5
// 399.948 us; speedup vs baseline: 1.1743x; 1.1743x over previous
//
#include <hip/hip_runtime.h>
#include <hip/hip_bf16.h>

typedef float  f32x4  __attribute__((ext_vector_type(4)));
typedef __bf16 bf16x8 __attribute__((ext_vector_type(8)));
typedef __bf16 bf16x4 __attribute__((ext_vector_type(4)));

#define D_  512
#define H_  8
#define HD_ 64
#define B_  256
#define N_  144
#define M_  (B_*N_)   // 36864

using gptr_t = const __attribute__((address_space(1))) char*;
using lptr_t = __attribute__((address_space(3))) char*;
#define GLDS16(gp, lp) __builtin_amdgcn_global_load_lds((gptr_t)(gp), (lptr_t)(lp), 16, 0, 0)

// ---------------- weight prep: f32 -> bf16 ----------------
__global__ void prep_weights_kernel(const float* __restrict__ kvw,
                                    const float* __restrict__ qw,
                                    const float* __restrict__ pw,
                                    __bf16* __restrict__ kvb,
                                    __bf16* __restrict__ qb,
                                    __bf16* __restrict__ pb) {
    int idx = blockIdx.x * 256 + threadIdx.x;   // 262144 threads, 4 elements each
    const float* s; __bf16* d; int off;
    if (idx < 131072)      { s = kvw; d = kvb; off = idx; }
    else if (idx < 196608) { s = qw;  d = qb;  off = idx - 131072; }
    else                   { s = pw;  d = pb;  off = idx - 196608; }
    f32x4 v = *(const f32x4*)(s + (size_t)off * 4);
    bf16x4 o;
    o[0] = (__bf16)v.x; o[1] = (__bf16)v.y; o[2] = (__bf16)v.z; o[3] = (__bf16)v.w;
    *(bf16x4*)(d + (size_t)off * 4) = o;
}

// ------------- activation prep: xb = bf16(x), ab = bf16(x + tf*topo) -------------
__global__ void prep_act_kernel(const float* __restrict__ x,
                                const float* __restrict__ topo,
                                const int* __restrict__ is_end,
                                __bf16* __restrict__ xb,
                                __bf16* __restrict__ ab) {
    const float tf = (is_end[0] != 0) ? 1.f : 0.f;
    const size_t total = (size_t)M_ * D_ / 8;   // 2359296 chunks of 8
    for (size_t i = (size_t)blockIdx.x * 256 + threadIdx.x; i < total;
         i += (size_t)gridDim.x * 256) {
        f32x4 a0 = *(const f32x4*)(x + i * 8);
        f32x4 a1 = *(const f32x4*)(x + i * 8 + 4);
        f32x4 t0 = *(const f32x4*)(topo + i * 8);
        f32x4 t1 = *(const f32x4*)(topo + i * 8 + 4);
        bf16x8 xo, ao;
#pragma unroll
        for (int j = 0; j < 4; ++j) {
            xo[j]     = (__bf16)a0[j];
            xo[j + 4] = (__bf16)a1[j];
            ao[j]     = (__bf16)(a0[j] + tf * t0[j]);
            ao[j + 4] = (__bf16)(a1[j] + tf * t1[j]);
        }
        *(bf16x8*)(xb + i * 8) = xo;
        *(bf16x8*)(ab + i * 8) = ao;
    }
}

// ---------------- bf16 GEMM, m97 structure: 128x128 tile, BK=64 ----------------
// global_load_lds(16B) -> linear LDS -> ds_read_b128 frags -> 16x16x32 MFMA.
// MODE 0: fused projections. nb<8: A=ab, B=kv_w rows -> K/V^T scatter.
//                            nb>=8: A=xb, B=q_w rows -> Q [B,H,N,64].
// MODE 1: out proj. A=attn_out(bf16), B=proj_w -> f32 out + bias.
template<int MODE>
__launch_bounds__(256, 3)
__global__ void mm_kernel(const __bf16* __restrict__ ab,
                          const __bf16* __restrict__ xb,
                          const __bf16* __restrict__ kvb,
                          const __bf16* __restrict__ qb,
                          __bf16* __restrict__ kout,
                          __bf16* __restrict__ vTout,
                          __bf16* __restrict__ qout,
                          const float* __restrict__ bias,
                          float* __restrict__ pout) {
    __shared__ __bf16 As[128 * 64];   // 16 KiB, linear (global_load_lds dest)
    __shared__ __bf16 Bs[128 * 64];   // 16 KiB

    const int tid  = threadIdx.x;
    const int lane = tid & 63;
    const int wid  = tid >> 6;
    const int lrow = lane & 15, lhi = lane >> 4;
    const int wr   = wid >> 1,  wc  = wid & 1;

    // bijective XCD swizzle: contiguous wg chunk per XCD; consecutive wg share mb
    const int NB  = (MODE == 0) ? 12 : 4;
    const int per = (MODE == 0) ? 432 : 144;   // nwg/8 (both divisible by 8)
    const int bid = blockIdx.x;
    const int wg  = (bid & 7) * per + (bid >> 3);
    const int mb  = wg / NB;
    const int nb  = wg - mb * NB;
    const int m0  = mb * 128;

    const __bf16* Ap;
    const __bf16* Bp;
    if (MODE == 0) {
        Ap = (nb < 8) ? ab : xb;
        Bp = (nb < 8) ? (kvb + (size_t)nb * 128 * D_) : (qb + (size_t)(nb - 8) * 128 * D_);
    } else {
        Ap = ab;                         // attn output (bf16)
        Bp = kvb + (size_t)nb * 128 * D_; // proj weights
    }

    f32x4 acc[4][4];
#pragma unroll
    for (int i = 0; i < 4; ++i)
#pragma unroll
        for (int j = 0; j < 4; ++j) acc[i][j] = (f32x4){0.f, 0.f, 0.f, 0.f};

    const int srow = lane >> 3;          // staging: lane's row within chunk
    const int scol = (lane & 7) * 16;    // byte col within 128-B row

    for (int kt = 0; kt < 8; ++kt) {
        const int k0 = kt * 64;
        const char* Agb = (const char*)(Ap + (size_t)m0 * D_ + k0);
        const char* Bgb = (const char*)(Bp + k0);
#pragma unroll
        for (int j = 0; j < 4; ++j) {
            const int chunk = wid * 4 + j;           // 0..15, 1 KiB each
            const int row   = chunk * 8 + srow;
            GLDS16(Agb + (size_t)row * (D_ * 2) + scol, (char*)As + chunk * 1024);
            GLDS16(Bgb + (size_t)row * (D_ * 2) + scol, (char*)Bs + chunk * 1024);
        }
        __syncthreads();   // compiler: s_waitcnt vmcnt(0) + barrier
#pragma unroll
        for (int kk = 0; kk < 2; ++kk) {
            bf16x8 af[4], bfr[4];
#pragma unroll
            for (int mi = 0; mi < 4; ++mi)
                af[mi] = *(const bf16x8*)((const char*)As +
                          (wr * 64 + mi * 16 + lrow) * 128 + kk * 64 + lhi * 16);
#pragma unroll
            for (int ni = 0; ni < 4; ++ni)
                bfr[ni] = *(const bf16x8*)((const char*)Bs +
                          (wc * 64 + ni * 16 + lrow) * 128 + kk * 64 + lhi * 16);
#pragma unroll
            for (int mi = 0; mi < 4; ++mi)
#pragma unroll
                for (int ni = 0; ni < 4; ++ni)
                    acc[mi][ni] = __builtin_amdgcn_mfma_f32_16x16x32_bf16(
                        af[mi], bfr[ni], acc[mi][ni], 0, 0, 0);
        }
        __syncthreads();
    }

    // ---- epilogue: C row = (lane>>4)*4+reg, col = lane&15 (m89-verified) ----
    float bv4[4];
    if (MODE == 1) {
#pragma unroll
        for (int ni = 0; ni < 4; ++ni) bv4[ni] = bias[nb * 128 + wc * 64 + ni * 16 + lrow];
    }
#pragma unroll
    for (int mi = 0; mi < 4; ++mi) {
#pragma unroll
        for (int reg = 0; reg < 4; ++reg) {
            int m  = m0 + wr * 64 + mi * 16 + lhi * 4 + reg;
            int bb = m / N_;
            int nn = m - bb * N_;
#pragma unroll
            for (int ni = 0; ni < 4; ++ni) {
                const int ol = wc * 64 + ni * 16 + lrow;   // 0..127 within n-tile
                float val = acc[mi][ni][reg];
                if (MODE == 0) {
                    const int o = nb * 128 + ol;
                    if (nb < 8) {
                        int hh = (o >> 6) & 7;
                        int dd = o & 63;
                        if (o < 512)
                            kout[(((size_t)bb * H_ + hh) * N_ + nn) * HD_ + dd] = (__bf16)val;
                        else
                            vTout[(((size_t)bb * H_ + hh) * HD_ + dd) * N_ + nn] = (__bf16)val;
                    } else {
                        int o2 = o - 1024;
                        int hh = o2 >> 6, dd = o2 & 63;
                        qout[(((size_t)bb * H_ + hh) * N_ + nn) * HD_ + dd] = (__bf16)val;
                    }
                } else {
                    pout[(size_t)m * D_ + nb * 128 + ol] = val + bv4[ni];
                }
            }
        }
    }
}

// ---------------- attention: one block per (b,h) ----------------
__launch_bounds__(256, 2)
__global__ void attn_kernel(const __bf16* __restrict__ qbuf,
                            const __bf16* __restrict__ kbuf,
                            const __bf16* __restrict__ vTbuf,
                            __bf16* __restrict__ aout) {
    __shared__ __bf16 Ks[144][72];     // 20736 B
    __shared__ __bf16 Vs[64][168];     // 21504 B (cols 144..167 zero)
    __shared__ __bf16 Ps[4][16][160];  // 20480 B per-wave P tiles

    const int tid  = threadIdx.x;
    const int lane = tid & 63, wid = tid >> 6;
    const int lrow = lane & 15, lhi = lane >> 4;
    const int bh = blockIdx.x;
    const int bb = bh >> 3, hh = bh & 7;

    const __bf16* kg = kbuf  + (size_t)bh * (N_ * HD_);
    const __bf16* vg = vTbuf + (size_t)bh * (N_ * HD_);
    const __bf16* qg = qbuf  + (size_t)bh * (N_ * HD_);

    for (int c = tid; c < 1152; c += 256) {       // K: 144x64
        int row = c >> 3, cc = c & 7;
        *(bf16x8*)&Ks[row][cc * 8] = *(const bf16x8*)(kg + row * 64 + cc * 8);
    }
    for (int c = tid; c < 1152; c += 256) {       // vT: 64x144
        int dd = c / 18, cc = c - dd * 18;
        *(bf16x8*)&Vs[dd][cc * 8] = *(const bf16x8*)(vg + dd * 144 + cc * 8);
    }
    bf16x8 z8;
#pragma unroll
    for (int i = 0; i < 8; ++i) z8[i] = (__bf16)0.f;
    if (tid < 192) {                              // zero pad cols of Vs
        int dd = tid / 3, cc = tid - dd * 3;
        *(bf16x8*)&Vs[dd][144 + cc * 8] = z8;
    }
    if (lhi < 2)                                  // zero pad cols of this wave's Ps
        *(bf16x8*)&Ps[wid][lrow][144 + lhi * 8] = z8;
    __syncthreads();

    const float sc = 0.125f * 1.44269504089f;     // scale * log2(e)

    for (int t = wid; t < 9; t += 4) {            // 16-row tiles of Q
        bf16x8 aq[2];
#pragma unroll
        for (int kk = 0; kk < 2; ++kk)
            aq[kk] = *(const bf16x8*)(qg + (t * 16 + lrow) * 64 + kk * 32 + lhi * 8);

        f32x4 s[9];
#pragma unroll
        for (int j = 0; j < 9; ++j) s[j] = (f32x4){0.f, 0.f, 0.f, 0.f};
#pragma unroll
        for (int j = 0; j < 9; ++j)
#pragma unroll
            for (int kk = 0; kk < 2; ++kk)
                s[j] = __builtin_amdgcn_mfma_f32_16x16x32_bf16(
                    aq[kk], *(const bf16x8*)&Ks[j * 16 + lrow][kk * 32 + lhi * 8], s[j], 0, 0, 0);

        float inv[4];
#pragma unroll
        for (int reg = 0; reg < 4; ++reg) {
            float mx = s[0][reg];
#pragma unroll
            for (int j = 1; j < 9; ++j) mx = fmaxf(mx, s[j][reg]);
#pragma unroll
            for (int off = 1; off < 16; off <<= 1) mx = fmaxf(mx, __shfl_xor(mx, off, 16));
            float sum = 0.f;
#pragma unroll
            for (int j = 0; j < 9; ++j) {
                float p = exp2f((s[j][reg] - mx) * sc);
                s[j][reg] = p;
                sum += p;
            }
#pragma unroll
            for (int off = 1; off < 16; off <<= 1) sum += __shfl_xor(sum, off, 16);
            inv[reg] = 1.f / sum;
        }
#pragma unroll
        for (int j = 0; j < 9; ++j)
#pragma unroll
            for (int reg = 0; reg < 4; ++reg)
                Ps[wid][lhi * 4 + reg][j * 16 + lrow] = (__bf16)(s[j][reg] * inv[reg]);

        // PV: out[16,64] = P[16,160] @ V[160,64]  (K padded with zeros)
#pragma unroll
        for (int dc = 0; dc < 4; ++dc) {
            f32x4 o4 = (f32x4){0.f, 0.f, 0.f, 0.f};
#pragma unroll
            for (int kc = 0; kc < 5; ++kc)
                o4 = __builtin_amdgcn_mfma_f32_16x16x32_bf16(
                    *(const bf16x8*)&Ps[wid][lrow][kc * 32 + lhi * 8],
                    *(const bf16x8*)&Vs[dc * 16 + lrow][kc * 32 + lhi * 8], o4, 0, 0, 0);
#pragma unroll
            for (int reg = 0; reg < 4; ++reg) {
                int nn = t * 16 + lhi * 4 + reg;
                int dd = dc * 16 + lrow;
                aout[((size_t)bb * N_ + nn) * D_ + hh * HD_ + dd] = (__bf16)o4[reg];
            }
        }
    }
}

extern "C" void kernel_launch(void* const* d_in, const int* in_sizes, int n_in,
                              void* d_out, int out_size, void* d_ws, size_t ws_size,
                              hipStream_t stream) {
    const float* x      = (const float*)d_in[0];
    const float* topo   = (const float*)d_in[1];
    const float* kvw    = (const float*)d_in[2];
    const float* qw     = (const float*)d_in[3];
    const float* pw     = (const float*)d_in[4];
    const float* pb     = (const float*)d_in[5];
    const int*   is_end = (const int*)d_in[6];
    float* out = (float*)d_out;

    char* ws = (char*)d_ws;
    __bf16* kvb = (__bf16*)(ws);                       // 1 MiB
    __bf16* qb  = (__bf16*)(ws + (1u << 20));          // 512 KiB
    __bf16* pwb = (__bf16*)(ws + (1u << 20) + 524288); // 512 KiB
    size_t off = (1u << 20) + 2 * 524288;
    const size_t BUF = (size_t)M_ * D_ * 2;            // 37748736 B each
    __bf16* xb    = (__bf16*)(ws + off); off += BUF;   // bf16(x); reused as abuf later
    __bf16* ab    = (__bf16*)(ws + off); off += BUF;   // bf16(x + tf*topo)
    __bf16* kbuf  = (__bf16*)(ws + off); off += BUF;
    __bf16* vTbuf = (__bf16*)(ws + off); off += BUF;
    __bf16* qbuf  = (__bf16*)(ws + off); off += BUF;
    __bf16* abuf  = xb;   // xb dead after mm<0>; alias to stay within ws

    prep_weights_kernel<<<1024, 256, 0, stream>>>(kvw, qw, pw, kvb, qb, pwb);
    prep_act_kernel<<<2048, 256, 0, stream>>>(x, topo, is_end, xb, ab);
    mm_kernel<0><<<3456, 256, 0, stream>>>(ab, xb, kvb, qb,
                                           kbuf, vTbuf, qbuf, nullptr, nullptr);
    attn_kernel<<<2048, 256, 0, stream>>>(qbuf, kbuf, vTbuf, abuf);
    mm_kernel<1><<<1152, 256, 0, stream>>>(abuf, nullptr, pwb, nullptr,
                                           nullptr, nullptr, nullptr, pb, out);
}